// Round 1
// baseline (453.983 us; speedup 1.0000x reference)
//
#include <hip/hip_runtime.h>
#include <math.h>

#define NEGINF (-INFINITY)

typedef unsigned long long u64;
typedef unsigned int u32;

#define RST 128  // rows staged in LDS (128 KiB dynamic shared)

// ---- 64-bit argmax keys ----------------------------------------------------
// key = (f32 bits of value) << 32 | (0xFFFF ^ (row<<8|col)).
// Values are softmax outputs (strictly > 0, min entry ~e^-10 for N(0,1)
// logits), so positive-float bit patterns order correctly as unsigned ints.
// The inverted flat index makes u64-max pick the LOWEST flat index on exact
// value ties (matches jnp.argmax first-occurrence).
// key == 0 encodes dead/excluded rows (any live value gives key > 2^32).

__device__ __forceinline__ u64 pack_key(float v, int flat) {
    u64 k = ((u64)__float_as_uint(v) << 32) | (u64)(u32)(0xFFFF ^ flat);
    return (v > 0.f) ? k : 0ull;
}

// One 64-bit DPP max stage: bound_ctrl=false + old=x makes invalid source
// lanes contribute x itself (identity for max). Both halves move from the
// same source lane, so the (hi,lo) pair stays consistent.
template <int CTRL>
__device__ __forceinline__ u64 dppmax64(u64 x) {
    int lo = (int)(u32)x;
    int hi = (int)(u32)(x >> 32);
    int ylo = __builtin_amdgcn_update_dpp(lo, lo, CTRL, 0xf, 0xf, false);
    int yhi = __builtin_amdgcn_update_dpp(hi, hi, CTRL, 0xf, 0xf, false);
    u64 y = ((u64)(u32)yhi << 32) | (u64)(u32)ylo;
    return y > x ? y : x;
}

// Wave64 max of u64 keys via DPP (row_shr 1/2/4/8, row_bcast 15/31), result
// broadcast from lane 63. No ballot / dynamic readlane / tie loop needed:
// the packed key already encodes exact argmax semantics.
__device__ __forceinline__ u64 wave_keymax(u64 x) {
    x = dppmax64<0x111>(x);   // row_shr:1
    x = dppmax64<0x112>(x);   // row_shr:2
    x = dppmax64<0x114>(x);   // row_shr:4
    x = dppmax64<0x118>(x);   // row_shr:8
    x = dppmax64<0x142>(x);   // row_bcast:15
    x = dppmax64<0x143>(x);   // row_bcast:31
    int lo = __builtin_amdgcn_readlane((int)(u32)x, 63);
    int hi = __builtin_amdgcn_readlane((int)(u32)(x >> 32), 63);
    return ((u64)(u32)hi << 32) | (u64)(u32)lo;
}

// Finish a rescan of row `drow`: w holds this lane's 4 columns
// (cols 4*lane..4*lane+3), colmask holds this lane's 4 column-taken bits.
// Reduces the masked row max, writes the fresh key back to the owner lane's
// cache, and returns the reduced key (wave-uniform).
__device__ __forceinline__ u64 rescan_finish(int drow, float4 w, u32 colmask,
                                             int lane, u64 (&key)[4]) {
    const int base = (drow << 8) | (lane << 2);
    u64 k = 0, t;
    t = pack_key(w.x, base + 0); if (!(colmask & 1u) && t > k) k = t;
    t = pack_key(w.y, base + 1); if (!(colmask & 2u) && t > k) k = t;
    t = pack_key(w.z, base + 2); if (!(colmask & 4u) && t > k) k = t;
    t = pack_key(w.w, base + 3); if (!(colmask & 8u) && t > k) k = t;
    u64 kr = wave_keymax(k);
    if (lane == (drow & 63)) {
        const int rj = drow >> 6;
#pragma unroll
        for (int j = 0; j < 4; ++j) if (rj == j) key[j] = kr;
    }
    return kr;
}

// One wave (64 lanes) per batch. Lane l owns rows {j*64+l : j=0..3} (cached
// packed argmax key per row) and column-mask bits for cols 4l..4l+3.
// Rows 0..RSTT-1 are additionally staged in LDS (chunk-XOR swizzled so the
// per-lane strided init writes spread across banks); rescans of those rows
// read LDS (~150 cy) instead of global (~500-800 cy).
// Rescans are pipelined: loads are ISSUED when a row goes dirty (row
// temporarily excluded via key=0), and CONSUMED after the next step's main
// argmax, hiding the load latency under the reduction.
template <int RSTT>
__global__ __launch_bounds__(64, 1) void greedy_perm_kernel(
        const float* __restrict__ soft, float* __restrict__ out) {
    extern __shared__ float smem[];           // RSTT rows x 256 floats
    const int b = blockIdx.x;
    const int lane = threadIdx.x;
    const size_t base = (size_t)b << 16;      // b * 256 * 256
    const float* sc = soft + base;
    float* ob = out + base;

    float vmax[4];
    int cbest[4];
#pragma unroll
    for (int j = 0; j < 4; ++j) { vmax[j] = NEGINF; cbest[j] = 0; }

    const float4 zero4 = make_float4(0.f, 0.f, 0.f, 0.f);

    // ---- initial per-row scans, 16 loads in flight, fused zero-fill of out,
    // ---- fused LDS staging of rows 0..RSTT-1 ----
    for (int k = 0; k < 64; k += 4) {
        float4 w[4][4];
#pragma unroll
        for (int j = 0; j < 4; ++j) {
            const float4* rp = (const float4*)(sc + (size_t)(j * 64 + lane) * 256);
#pragma unroll
            for (int kk = 0; kk < 4; ++kk) w[j][kk] = rp[k + kk];
        }
#pragma unroll
        for (int j = 0; j < 4; ++j) {
            float4* op = (float4*)(ob + (size_t)(j * 64 + lane) * 256);
#pragma unroll
            for (int kk = 0; kk < 4; ++kk) op[k + kk] = zero4;
        }
        if (RSTT > 0) {
            // row = j*64+lane (j=0,1); store chunk c at position c^lane so the
            // 64 lanes' 16B writes spread over all bank groups (2 lanes/bank).
#pragma unroll
            for (int j = 0; j < 2; ++j) {
                float* lp = &smem[(j * 64 + lane) << 8];
#pragma unroll
                for (int kk = 0; kk < 4; ++kk)
                    *(float4*)&lp[((k + kk) ^ lane) << 2] = w[j][kk];
            }
        }
#pragma unroll
        for (int j = 0; j < 4; ++j) {
#pragma unroll
            for (int kk = 0; kk < 4; ++kk) {
                const float4 ww = w[j][kk];
                const int bc = 4 * (k + kk);
                if (ww.x > vmax[j]) { vmax[j] = ww.x; cbest[j] = bc + 0; }
                if (ww.y > vmax[j]) { vmax[j] = ww.y; cbest[j] = bc + 1; }
                if (ww.z > vmax[j]) { vmax[j] = ww.z; cbest[j] = bc + 2; }
                if (ww.w > vmax[j]) { vmax[j] = ww.w; cbest[j] = bc + 3; }
            }
        }
    }

    u64 key[4];
#pragma unroll
    for (int j = 0; j < 4; ++j)
        key[j] = pack_key(vmax[j], ((j * 64 + lane) << 8) | cbest[j]);

    // Drain zero-stores before any 1.0 store can target the same address.
    __threadfence_block();

    u32 colmask = 0;             // 4 bits: cols 4*lane..4*lane+3 assigned?
    int drow0 = -1, drow1 = -1, drow2 = -1;   // pending rescan slots
    float4 d0 = zero4, d1 = zero4, d2 = zero4;

    // ---- 256 sequential greedy steps ----
    for (int step = 0; step < 256; ++step) {
        // A: main argmax over cached keys (pending/dead rows are key==0)
        u64 ka = key[0] > key[1] ? key[0] : key[1];
        u64 kb = key[2] > key[3] ? key[2] : key[3];
        u64 kw = wave_keymax(ka > kb ? ka : kb);

        // B: finish pending rescans (loads have been in flight since the
        // previous step's E phase, hidden under A), merge exactly.
        if (drow0 >= 0) {
            u64 kr = rescan_finish(drow0, d0, colmask, lane, key);
            if (kr > kw) kw = kr;
            drow0 = -1;
        }
        if (drow1 >= 0) {
            u64 kr = rescan_finish(drow1, d1, colmask, lane, key);
            if (kr > kw) kw = kr;
            drow1 = -1;
        }
        if (drow2 >= 0) {
            u64 kr = rescan_finish(drow2, d2, colmask, lane, key);
            if (kr > kw) kw = kr;
            drow2 = -1;
        }

        // C: winner
        const int gf = 0xFFFF ^ (int)(u32)(kw & 0xFFFFull);
        const int r  = gf >> 8;
        const int cc = gf & 255;
        if (lane == 0) ob[gf] = 1.0f;        // hard[r][cc] = 1
        {
            const bool amr = (lane == (r & 63));
            const int rj = r >> 6;
#pragma unroll
            for (int j = 0; j < 4; ++j) if (amr && rj == j) key[j] = 0;  // row dead
        }
        if (lane == (cc >> 2)) colmask |= 1u << (cc & 3);

        // D: rows whose cached argmax column just got taken
        const u32 lowb = (u32)(0xFF ^ cc);
        u64 bm[4];
#pragma unroll
        for (int j = 0; j < 4; ++j) {
            const bool dj = (key[j] > 0xFFFFull) && (((u32)key[j] & 0xFFu) == lowb);
            bm[j] = __ballot(dj);
        }

        // E: issue rescan loads; park up to 3 in pending slots (consumed at
        // next step's B), process overflow synchronously (rare).
        int nass = 0;
#pragma unroll
        for (int j = 0; j < 4; ++j) {
            u64 m = bm[j];
            while (m) {
                const int ln = (int)__builtin_ctzll(m); m &= m - 1;
                const int row = j * 64 + ln;
                if (nass == 0) {
                    drow0 = row;
                    d0 = (RSTT > 0 && row < RSTT)
                        ? *(const float4*)&smem[(row << 8) | (((lane ^ ln) & 63) << 2)]
                        : *(const float4*)(sc + ((size_t)row << 8) + (lane << 2));
                } else if (nass == 1) {
                    drow1 = row;
                    d1 = (RSTT > 0 && row < RSTT)
                        ? *(const float4*)&smem[(row << 8) | (((lane ^ ln) & 63) << 2)]
                        : *(const float4*)(sc + ((size_t)row << 8) + (lane << 2));
                } else if (nass == 2) {
                    drow2 = row;
                    d2 = (RSTT > 0 && row < RSTT)
                        ? *(const float4*)&smem[(row << 8) | (((lane ^ ln) & 63) << 2)]
                        : *(const float4*)(sc + ((size_t)row << 8) + (lane << 2));
                } else {
                    // synchronous fallback: resolve immediately (old path)
                    float4 w = (RSTT > 0 && row < RSTT)
                        ? *(const float4*)&smem[(row << 8) | (((lane ^ ln) & 63) << 2)]
                        : *(const float4*)(sc + ((size_t)row << 8) + (lane << 2));
                    rescan_finish(row, w, colmask, lane, key);
                }
                if (nass < 3 && lane == ln) {
                    // exclude pending row from next A (restored at next B)
#pragma unroll
                    for (int jj = 0; jj < 4; ++jj) if (jj == j) key[jj] = 0;
                }
                ++nass;
            }
        }
    }
}

extern "C" void kernel_launch(void* const* d_in, const int* in_sizes, int n_in,
                              void* d_out, int out_size, void* d_ws, size_t ws_size,
                              hipStream_t stream) {
    const float* soft = (const float*)d_in[0];
    float* out = (float*)d_out;
    const int n_batches = in_sizes[0] >> 16;   // elements / (256*256)

    // 128 KiB dynamic LDS needs the attribute raised once; fall back to the
    // no-staging instantiation if the runtime refuses.
    static int use_lds = -1;
    if (use_lds < 0) {
        hipError_t e = hipFuncSetAttribute(
            reinterpret_cast<const void*>(greedy_perm_kernel<RST>),
            hipFuncAttributeMaxDynamicSharedMemorySize, RST * 256 * 4);
        use_lds = (e == hipSuccess) ? 1 : 0;
    }
    if (use_lds)
        greedy_perm_kernel<RST><<<n_batches, 64, RST * 256 * 4, stream>>>(soft, out);
    else
        greedy_perm_kernel<0><<<n_batches, 64, 0, stream>>>(soft, out);
}